// Round 1
// baseline (1498.632 us; speedup 1.0000x reference)
//
#include <hip/hip_runtime.h>
#include <cstdint>
#include <cmath>

#define BT 8192   // tokens
#define DD 1024   // model dim
#define HH 4096   // hidden dim
#define EE 8      // experts

typedef __attribute__((ext_vector_type(8))) short short8;
typedef __attribute__((ext_vector_type(4))) float f32x4;
typedef unsigned short u16;
typedef unsigned int u32;

// round-to-nearest-even fp32 -> bf16 (inputs are finite; no NaN path needed)
__device__ __forceinline__ u16 f2bf(float f) {
    u32 u = __float_as_uint(f);
    u += 0x7FFFu + ((u >> 16) & 1u);
    return (u16)(u >> 16);
}

// async global->LDS, 16B per lane; LDS dest is wave-uniform base + lane*16
__device__ __forceinline__ void gld_lds16(const void* g, void* l) {
    __builtin_amdgcn_global_load_lds((__attribute__((address_space(1))) void*)g,
                                     (__attribute__((address_space(3))) void*)l,
                                     16, 0, 0);
}

// ---------------- fp32 -> bf16 bulk convert (8 elems/thread) ----------------
__global__ void cvt_kernel(const float* __restrict__ src, u16* __restrict__ dst, int n8) {
    int i = blockIdx.x * blockDim.x + threadIdx.x;
    if (i >= n8) return;
    size_t base = (size_t)i * 8;
    float4 a = *(const float4*)(src + base);
    float4 b = *(const float4*)(src + base + 4);
    uint4 o;
    o.x = (u32)f2bf(a.x) | ((u32)f2bf(a.y) << 16);
    o.y = (u32)f2bf(a.z) | ((u32)f2bf(a.w) << 16);
    o.z = (u32)f2bf(b.x) | ((u32)f2bf(b.y) << 16);
    o.w = (u32)f2bf(b.z) | ((u32)f2bf(b.w) << 16);
    *(uint4*)(dst + base) = o;
}

// ---------------- gating: fp64 logits, top-2, softmax, scatter lists --------
__global__ void gating_kernel(const float* __restrict__ x, const float* __restrict__ wg,
                              float* __restrict__ gate_arr, int* __restrict__ list,
                              int* __restrict__ counts, float* __restrict__ importance) {
    int wave = (blockIdx.x * blockDim.x + threadIdx.x) >> 6;  // one wave per token
    int lane = threadIdx.x & 63;
    if (wave >= BT) return;
    const float* xr = x + (size_t)wave * DD;
    double acc[EE];
#pragma unroll
    for (int e = 0; e < EE; ++e) acc[e] = 0.0;
    for (int i = lane; i < DD; i += 64) {
        double xv = (double)xr[i];
#pragma unroll
        for (int e = 0; e < EE; ++e)
            acc[e] += xv * (double)wg[e * DD + i];
    }
#pragma unroll
    for (int e = 0; e < EE; ++e) {
        double v = acc[e];
        for (int off = 32; off; off >>= 1) v += __shfl_down(v, off, 64);
        acc[e] = v;  // lane 0 holds the sum
    }
    if (lane == 0) {
        int i0 = 0; double v0 = acc[0];
        for (int e = 1; e < EE; ++e) if (acc[e] > v0) { v0 = acc[e]; i0 = e; }
        int i1 = -1; double v1 = -1e300;
        for (int e = 0; e < EE; ++e) { if (e == i0) continue; if (acc[e] > v1) { v1 = acc[e]; i1 = e; } }
        double e1 = exp(v1 - v0);
        double s = 1.0 + e1;
        float g0 = (float)(1.0 / s);
        float g1 = (float)(e1 / s);
        gate_arr[2 * wave]     = g0;
        gate_arr[2 * wave + 1] = g1;
        atomicAdd(&importance[i0], g0);
        atomicAdd(&importance[i1], g1);
        int p0 = atomicAdd(&counts[i0], 1);
        list[i0 * BT + p0] = (wave << 1);
        int p1 = atomicAdd(&counts[i1], 1);
        list[i1 * BT + p1] = (wave << 1) | 1;
    }
}

// ---------------- loss = 0.01*(cv^2(importance)+cv^2(load)) -----------------
__global__ void loss_kernel(const int* __restrict__ counts, const float* __restrict__ importance,
                            float* __restrict__ out_loss) {
    if (threadIdx.x == 0 && blockIdx.x == 0) {
        double mi = 0, ml = 0;
        for (int e = 0; e < EE; e++) { mi += (double)importance[e]; ml += (double)counts[e]; }
        mi /= EE; ml /= EE;
        double vi = 0, vl = 0;
        for (int e = 0; e < EE; e++) {
            double di = (double)importance[e] - mi; vi += di * di;
            double dl = (double)counts[e] - ml;     vl += dl * dl;
        }
        vi /= (EE - 1); vl /= (EE - 1);
        double cv_i = vi / (mi * mi + 1e-10);
        double cv_l = vl / (ml * ml + 1e-10);
        *out_loss = (float)((cv_i + cv_l) * 0.01);
    }
}

// ---------------- gathered-row MFMA GEMM (m97 structure) --------------------
// C[m,n] = sum_k A[row(m), k] * W[e][n, k]  (both K-contiguous, NT layout)
// PASS_A: out = gelu(C + fc1_b) -> bf16 h[entry];  else out = C + fc2_b -> fp32 o[entry]
template <int K, int NT, bool PASS_A>
__global__ __launch_bounds__(256) void moe_gemm(const u16* __restrict__ Asrc,
                                                const u16* __restrict__ Bsrc,
                                                const float* __restrict__ bias,
                                                const int* __restrict__ list,
                                                const int* __restrict__ counts,
                                                u16* __restrict__ outB,
                                                float* __restrict__ outF) {
    const int e = blockIdx.z;
    const int cnt = counts[e];
    const int mbase = blockIdx.y * 128;
    if (mbase >= cnt) return;
    const int nbase = blockIdx.x * 128;
    const int tid = threadIdx.x;
    const int lane = tid & 63;
    const int wv = tid >> 6;

    // LDS tiles in 16B-chunk layout: chunk c = kchunk*128 + row  (conflict-free
    // for both global_load_lds (lane-contiguous) and ds_read_b128 frag reads)
    __shared__ u16 As[128 * 32];
    __shared__ u16 Bs[128 * 32];
    __shared__ int rows_lds[128];

    if (tid < 128) {
        int m = mbase + tid;
        if (m >= cnt) m = cnt - 1;  // clamp: loads valid, stores guarded
        rows_lds[tid] = list[e * BT + m];
    }
    __syncthreads();

    const int myrow = tid & 127;          // row of my two chunks
    const int kch = tid >> 7;             // kchunk 0/1; second chunk is +2
    const int entry_my = rows_lds[myrow];
    const size_t arow = PASS_A ? (size_t)(entry_my >> 1) : (size_t)entry_my;
    const u16* aptr = Asrc + arow * (size_t)K + kch * 8;
    const u16* bptr = Bsrc + ((size_t)e * NT + nbase + myrow) * (size_t)K + kch * 8;

    f32x4 acc[4][4] = {};
    const int moff = (wv >> 1) * 64;
    const int noff = (wv & 1) * 64;
    const int kq = lane >> 4;
    const int rsub = lane & 15;

    for (int k0 = 0; k0 < K; k0 += 32) {
        gld_lds16(aptr + k0,      &As[tid * 8]);
        gld_lds16(aptr + k0 + 16, &As[(tid + 256) * 8]);
        gld_lds16(bptr + k0,      &Bs[tid * 8]);
        gld_lds16(bptr + k0 + 16, &Bs[(tid + 256) * 8]);
        __syncthreads();   // drains vmcnt before barrier -> LDS tiles complete
        short8 af[4], bfr[4];
#pragma unroll
        for (int mi = 0; mi < 4; mi++)
            af[mi] = *(const short8*)&As[(kq * 128 + moff + mi * 16 + rsub) * 8];
#pragma unroll
        for (int ni = 0; ni < 4; ni++)
            bfr[ni] = *(const short8*)&Bs[(kq * 128 + noff + ni * 16 + rsub) * 8];
#pragma unroll
        for (int mi = 0; mi < 4; mi++)
#pragma unroll
            for (int ni = 0; ni < 4; ni++)
                acc[mi][ni] = __builtin_amdgcn_mfma_f32_16x16x32_bf16(af[mi], bfr[ni], acc[mi][ni], 0, 0, 0);
        __syncthreads();
    }

    // epilogue: C/D layout col = lane&15, row = (lane>>4)*4 + reg  [m89-verified]
    const int rq = (lane >> 4) * 4;
    float bvals[4];
#pragma unroll
    for (int ni = 0; ni < 4; ni++)
        bvals[ni] = bias[(size_t)e * NT + nbase + noff + ni * 16 + rsub];
#pragma unroll
    for (int mi = 0; mi < 4; mi++) {
#pragma unroll
        for (int r = 0; r < 4; r++) {
            int m = moff + mi * 16 + rq + r;
            if (mbase + m < cnt) {
                int entry = rows_lds[m];
#pragma unroll
                for (int ni = 0; ni < 4; ni++) {
                    int n = nbase + noff + ni * 16 + rsub;
                    float v = acc[mi][ni][r] + bvals[ni];
                    if constexpr (PASS_A) {
                        v = 0.5f * v * (1.0f + erff(v * 0.7071067811865476f));  // exact gelu
                        outB[(size_t)entry * NT + n] = f2bf(v);
                    } else {
                        outF[(size_t)entry * NT + n] = v;
                    }
                }
            }
        }
    }
}

// ---------------- softmax over D for both slots + weighted combine + log ----
__global__ void combine_kernel(const float* __restrict__ o, const float* __restrict__ gates,
                               float* __restrict__ y) {
    const int b = blockIdx.x;
    const int tid = threadIdx.x;
    const int lane = tid & 63, wv = tid >> 6;
    const float* r0 = o + (size_t)(2 * b) * DD;
    const float* r1 = r0 + DD;
    float v0[4], v1[4];
#pragma unroll
    for (int j = 0; j < 4; j++) { v0[j] = r0[tid + 256 * j]; v1[j] = r1[tid + 256 * j]; }
    float m0 = fmaxf(fmaxf(v0[0], v0[1]), fmaxf(v0[2], v0[3]));
    float m1 = fmaxf(fmaxf(v1[0], v1[1]), fmaxf(v1[2], v1[3]));
#pragma unroll
    for (int off = 32; off; off >>= 1) {
        m0 = fmaxf(m0, __shfl_xor(m0, off, 64));
        m1 = fmaxf(m1, __shfl_xor(m1, off, 64));
    }
    __shared__ float sred[2][4];
    if (lane == 0) { sred[0][wv] = m0; sred[1][wv] = m1; }
    __syncthreads();
    m0 = fmaxf(fmaxf(sred[0][0], sred[0][1]), fmaxf(sred[0][2], sred[0][3]));
    m1 = fmaxf(fmaxf(sred[1][0], sred[1][1]), fmaxf(sred[1][2], sred[1][3]));
    float p0[4], p1[4], s0 = 0.f, s1 = 0.f;
#pragma unroll
    for (int j = 0; j < 4; j++) {
        p0[j] = expf(v0[j] - m0); s0 += p0[j];
        p1[j] = expf(v1[j] - m1); s1 += p1[j];
    }
#pragma unroll
    for (int off = 32; off; off >>= 1) {
        s0 += __shfl_xor(s0, off, 64);
        s1 += __shfl_xor(s1, off, 64);
    }
    __shared__ float sred2[2][4];
    if (lane == 0) { sred2[0][wv] = s0; sred2[1][wv] = s1; }
    __syncthreads();
    s0 = sred2[0][0] + sred2[0][1] + sred2[0][2] + sred2[0][3];
    s1 = sred2[1][0] + sred2[1][1] + sred2[1][2] + sred2[1][3];
    const float c0 = gates[2 * b] / s0;
    const float c1 = gates[2 * b + 1] / s1;
#pragma unroll
    for (int j = 0; j < 4; j++) {
        float c = p0[j] * c0 + p1[j] * c1;
        if (c == 0.f) c = 2.2204460492503131e-16f;  // np.finfo(float64).eps
        y[(size_t)b * DD + tid + 256 * j] = logf(c);
    }
}

extern "C" void kernel_launch(void* const* d_in, const int* in_sizes, int n_in,
                              void* d_out, int out_size, void* d_ws, size_t ws_size,
                              hipStream_t stream) {
    const float* x     = (const float*)d_in[0];
    const float* wgate = (const float*)d_in[1];
    const float* fc1w  = (const float*)d_in[2];
    const float* fc1b  = (const float*)d_in[3];
    const float* fc2w  = (const float*)d_in[4];
    const float* fc2b  = (const float*)d_in[5];
    float* out = (float*)d_out;

    char* ws = (char*)d_ws;
    const size_t MB = 1024 * 1024;
    // layout (273 MB total):
    //   [0,64MB)    w1 bf16   -- reused as o (fp32, 2B x D) after pass A is done
    //   [64,128MB)  w2 bf16
    //   [128,144MB) x bf16
    //   [144,272MB) h bf16 (2B x H), row = 2*b + slot
    //   [272MB+)    meta: counts(32B) importance(32B) gates(64KB) list(256KB)
    u16* w1b   = (u16*)(ws);
    float* o   = (float*)(ws);
    u16* w2b   = (u16*)(ws + 64 * MB);
    u16* xb    = (u16*)(ws + 128 * MB);
    u16* h     = (u16*)(ws + 144 * MB);
    char* meta = ws + 272 * MB;
    int* counts       = (int*)meta;
    float* importance = (float*)(meta + 32);
    float* gate_arr   = (float*)(meta + 64);
    int* list         = (int*)(meta + 64 + (size_t)2 * BT * 4);

    hipMemsetAsync(meta, 0, 64, stream);  // counts + importance
    cvt_kernel<<<(BT * DD / 8 + 255) / 256, 256, 0, stream>>>(x, xb, BT * DD / 8);
    cvt_kernel<<<(EE * HH * DD / 8 + 255) / 256, 256, 0, stream>>>(fc1w, w1b, EE * HH * DD / 8);
    cvt_kernel<<<(EE * DD * HH / 8 + 255) / 256, 256, 0, stream>>>(fc2w, w2b, EE * DD * HH / 8);
    gating_kernel<<<BT / 4, 256, 0, stream>>>(x, wgate, gate_arr, list, counts, importance);
    loss_kernel<<<1, 64, 0, stream>>>(counts, importance, out + (size_t)BT * DD);
    // pass A: h = gelu(x @ fc1_w^T + fc1_b), only for selected (token, expert)
    moe_gemm<DD, HH, true><<<dim3(HH / 128, BT / 128, EE), 256, 0, stream>>>(
        xb, w1b, fc1b, list, counts, h, nullptr);
    // pass B: o = h @ fc2_w^T + fc2_b   (o aliases w1b region; w1 no longer needed)
    moe_gemm<HH, DD, false><<<dim3(DD / 128, BT / 128, EE), 256, 0, stream>>>(
        h, w2b, fc2b, list, counts, nullptr, o);
    combine_kernel<<<BT, 256, 0, stream>>>(o, gate_arr, out);
}

// Round 2
// 1322.317 us; speedup vs baseline: 1.1333x; 1.1333x over previous
//
#include <hip/hip_runtime.h>
#include <cstdint>
#include <cmath>

#define BT 8192   // tokens
#define DD 1024   // model dim
#define HH 4096   // hidden dim
#define EE 8      // experts

typedef __attribute__((ext_vector_type(8))) short short8;
typedef __attribute__((ext_vector_type(4))) float f32x4;
typedef unsigned short u16;
typedef unsigned int u32;

// round-to-nearest-even fp32 -> bf16 (inputs are finite; no NaN path needed)
__device__ __forceinline__ u16 f2bf(float f) {
    u32 u = __float_as_uint(f);
    u += 0x7FFFu + ((u >> 16) & 1u);
    return (u16)(u >> 16);
}

// async global->LDS, 16B per lane; LDS dest is wave-uniform base + lane*16
__device__ __forceinline__ void gld_lds16(const void* g, void* l) {
    __builtin_amdgcn_global_load_lds((__attribute__((address_space(1))) void*)g,
                                     (__attribute__((address_space(3))) void*)l,
                                     16, 0, 0);
}

// ---------------- fp32 -> bf16 bulk convert (8 elems/thread) ----------------
__global__ void cvt_kernel(const float* __restrict__ src, u16* __restrict__ dst, int n8) {
    int i = blockIdx.x * blockDim.x + threadIdx.x;
    if (i >= n8) return;
    size_t base = (size_t)i * 8;
    float4 a = *(const float4*)(src + base);
    float4 b = *(const float4*)(src + base + 4);
    uint4 o;
    o.x = (u32)f2bf(a.x) | ((u32)f2bf(a.y) << 16);
    o.y = (u32)f2bf(a.z) | ((u32)f2bf(a.w) << 16);
    o.z = (u32)f2bf(b.x) | ((u32)f2bf(b.y) << 16);
    o.w = (u32)f2bf(b.z) | ((u32)f2bf(b.w) << 16);
    *(uint4*)(dst + base) = o;
}

// ---------------- gating: fp64 logits, top-2, softmax, build lists ----------
__global__ void gating_kernel(const float* __restrict__ x, const float* __restrict__ wg,
                              float* __restrict__ gate_arr, int* __restrict__ list,
                              int* __restrict__ info,
                              int* __restrict__ counts, float* __restrict__ importance) {
    int wave = (blockIdx.x * blockDim.x + threadIdx.x) >> 6;  // one wave per token
    int lane = threadIdx.x & 63;
    if (wave >= BT) return;
    const float* xr = x + (size_t)wave * DD;
    double acc[EE];
#pragma unroll
    for (int e = 0; e < EE; ++e) acc[e] = 0.0;
    for (int i = lane; i < DD; i += 64) {
        double xv = (double)xr[i];
#pragma unroll
        for (int e = 0; e < EE; ++e)
            acc[e] += xv * (double)wg[e * DD + i];
    }
#pragma unroll
    for (int e = 0; e < EE; ++e) {
        double v = acc[e];
        for (int off = 32; off; off >>= 1) v += __shfl_down(v, off, 64);
        acc[e] = v;  // lane 0 holds the sum
    }
    if (lane == 0) {
        int i0 = 0; double v0 = acc[0];
        for (int e = 1; e < EE; ++e) if (acc[e] > v0) { v0 = acc[e]; i0 = e; }
        int i1 = -1; double v1 = -1e300;
        for (int e = 0; e < EE; ++e) { if (e == i0) continue; if (acc[e] > v1) { v1 = acc[e]; i1 = e; } }
        double e1 = exp(v1 - v0);
        double s = 1.0 + e1;
        float g0 = (float)(1.0 / s);
        float g1 = (float)(e1 / s);
        gate_arr[2 * wave]     = g0;
        gate_arr[2 * wave + 1] = g1;
        atomicAdd(&importance[i0], g0);
        atomicAdd(&importance[i1], g1);
        int p0 = atomicAdd(&counts[i0], 1);
        list[i0 * BT + p0] = wave;                 // token id
        int p1 = atomicAdd(&counts[i1], 1);
        list[i1 * BT + p1] = wave;
        info[2 * wave]     = (i0 << 16) | p0;      // (expert, position-in-list)
        info[2 * wave + 1] = (i1 << 16) | p1;
    }
}

// ------- loss = 0.01*(cv^2(importance)+cv^2(load)); also exclusive scan -----
__global__ void loss_kernel(const int* __restrict__ counts, const float* __restrict__ importance,
                            int* __restrict__ offs, float* __restrict__ out_loss) {
    if (threadIdx.x == 0 && blockIdx.x == 0) {
        double mi = 0, ml = 0;
        int off = 0;
        for (int e = 0; e < EE; e++) {
            offs[e] = off; off += counts[e];
            mi += (double)importance[e]; ml += (double)counts[e];
        }
        mi /= EE; ml /= EE;
        double vi = 0, vl = 0;
        for (int e = 0; e < EE; e++) {
            double di = (double)importance[e] - mi; vi += di * di;
            double dl = (double)counts[e] - ml;     vl += dl * dl;
        }
        vi /= (EE - 1); vl /= (EE - 1);
        double cv_i = vi / (mi * mi + 1e-10);
        double cv_l = vl / (ml * ml + 1e-10);
        *out_loss = (float)((cv_i + cv_l) * 0.01);
    }
}

// ------- gather x token rows into packed expert-major bf16 layout -----------
__global__ void gather_x_kernel(const float* __restrict__ x, const int* __restrict__ list,
                                const int* __restrict__ counts, const int* __restrict__ offs,
                                u16* __restrict__ xg) {
    int r = blockIdx.x;   // packed row, 0..2*BT-1
    int e = 0;
#pragma unroll
    for (int i = 1; i < EE; ++i) if (r >= offs[i]) e = i;
    int m = r - offs[e];
    if (m >= counts[e]) return;  // defensive; sum of counts == 2*BT
    int token = list[e * BT + m];
    const float* src = x + (size_t)token * DD;
    u16* dst = xg + (size_t)r * DD;
    int i = threadIdx.x * 4;
    float4 a = *(const float4*)(src + i);
    uint2 o;
    o.x = (u32)f2bf(a.x) | ((u32)f2bf(a.y) << 16);
    o.y = (u32)f2bf(a.z) | ((u32)f2bf(a.w) << 16);
    *(uint2*)(dst + i) = o;
}

// ---------------- packed-row MFMA GEMM (m97 structure) ----------------------
// C[m,n] = sum_k A[row(m), k] * W[e][n, k]  (both K-contiguous, NT layout)
// GATHER: A row from list (token ids); else A rows contiguous at offs[e]+mbase.
// GELU: out = gelu(C + bias) -> bf16;  else out = C + bias -> fp32
template <int K, int NT, bool GELU, bool GATHER>
__global__ __launch_bounds__(256) void moe_gemm(const u16* __restrict__ Asrc,
                                                const u16* __restrict__ Bsrc,
                                                const float* __restrict__ bias,
                                                const int* __restrict__ list,
                                                const int* __restrict__ counts,
                                                const int* __restrict__ offs,
                                                u16* __restrict__ outB,
                                                float* __restrict__ outF) {
    const int e = blockIdx.z;
    const int cnt = counts[e];
    const int mbase = blockIdx.y * 128;
    if (mbase >= cnt) return;
    const int mmax = cnt - mbase;            // valid rows in this tile
    const int rowbase = offs[e] + mbase;     // packed output row base
    const int nbase = blockIdx.x * 128;
    const int tid = threadIdx.x;
    const int lane = tid & 63;
    const int wv = tid >> 6;

    // LDS tiles in 16B-chunk layout: chunk c = kchunk*128 + row  (conflict-free
    // for both global_load_lds (lane-contiguous) and ds_read_b128 frag reads)
    __shared__ u16 As[128 * 32];
    __shared__ u16 Bs[128 * 32];
    __shared__ int rows_lds[128];

    if constexpr (GATHER) {
        if (tid < 128) {
            int m = min(tid, mmax - 1);
            rows_lds[tid] = list[e * BT + mbase + m];
        }
        __syncthreads();
    }

    const int myrow = tid & 127;          // row of my two chunks
    const int kch = tid >> 7;             // kchunk 0/1; second chunk is +2
    size_t arow;
    if constexpr (GATHER) arow = (size_t)rows_lds[myrow];
    else                  arow = (size_t)(rowbase + min(myrow, mmax - 1));
    const u16* aptr = Asrc + arow * (size_t)K + kch * 8;
    const u16* bptr = Bsrc + ((size_t)e * NT + nbase + myrow) * (size_t)K + kch * 8;

    f32x4 acc[4][4] = {};
    const int moff = (wv >> 1) * 64;
    const int noff = (wv & 1) * 64;
    const int kq = lane >> 4;
    const int rsub = lane & 15;

    for (int k0 = 0; k0 < K; k0 += 32) {
        gld_lds16(aptr + k0,      &As[tid * 8]);
        gld_lds16(aptr + k0 + 16, &As[(tid + 256) * 8]);
        gld_lds16(bptr + k0,      &Bs[tid * 8]);
        gld_lds16(bptr + k0 + 16, &Bs[(tid + 256) * 8]);
        __syncthreads();   // drains vmcnt before barrier -> LDS tiles complete
        short8 af[4], bfr[4];
#pragma unroll
        for (int mi = 0; mi < 4; mi++)
            af[mi] = *(const short8*)&As[(kq * 128 + moff + mi * 16 + rsub) * 8];
#pragma unroll
        for (int ni = 0; ni < 4; ni++)
            bfr[ni] = *(const short8*)&Bs[(kq * 128 + noff + ni * 16 + rsub) * 8];
#pragma unroll
        for (int mi = 0; mi < 4; mi++)
#pragma unroll
            for (int ni = 0; ni < 4; ni++)
                acc[mi][ni] = __builtin_amdgcn_mfma_f32_16x16x32_bf16(af[mi], bfr[ni], acc[mi][ni], 0, 0, 0);
        __syncthreads();
    }

    // epilogue: C/D layout col = lane&15, row = (lane>>4)*4 + reg  [m89-verified]
    const int rq = (lane >> 4) * 4;
    float bvals[4];
#pragma unroll
    for (int ni = 0; ni < 4; ni++)
        bvals[ni] = bias[(size_t)e * NT + nbase + noff + ni * 16 + rsub];
#pragma unroll
    for (int mi = 0; mi < 4; mi++) {
#pragma unroll
        for (int r = 0; r < 4; r++) {
            int m = moff + mi * 16 + rq + r;
            if (m < mmax) {
                size_t ro = (size_t)(rowbase + m);
#pragma unroll
                for (int ni = 0; ni < 4; ni++) {
                    int n = nbase + noff + ni * 16 + rsub;
                    float v = acc[mi][ni][r] + bvals[ni];
                    if constexpr (GELU) {
                        v = 0.5f * v * (1.0f + erff(v * 0.7071067811865476f));  // exact gelu
                        outB[ro * NT + n] = f2bf(v);
                    } else {
                        outF[ro * NT + n] = v;
                    }
                }
            }
        }
    }
}

// ---------------- softmax over D for both slots + weighted combine + log ----
__global__ void combine_kernel(const float* __restrict__ o, const float* __restrict__ gates,
                               const int* __restrict__ info, const int* __restrict__ offs,
                               float* __restrict__ y) {
    const int b = blockIdx.x;
    const int tid = threadIdx.x;
    const int lane = tid & 63, wv = tid >> 6;
    const int inf0 = info[2 * b], inf1 = info[2 * b + 1];
    const int r0i = offs[inf0 >> 16] + (inf0 & 0xffff);
    const int r1i = offs[inf1 >> 16] + (inf1 & 0xffff);
    const float* r0 = o + (size_t)r0i * DD;
    const float* r1 = o + (size_t)r1i * DD;
    float v0[4], v1[4];
#pragma unroll
    for (int j = 0; j < 4; j++) { v0[j] = r0[tid + 256 * j]; v1[j] = r1[tid + 256 * j]; }
    float m0 = fmaxf(fmaxf(v0[0], v0[1]), fmaxf(v0[2], v0[3]));
    float m1 = fmaxf(fmaxf(v1[0], v1[1]), fmaxf(v1[2], v1[3]));
#pragma unroll
    for (int off = 32; off; off >>= 1) {
        m0 = fmaxf(m0, __shfl_xor(m0, off, 64));
        m1 = fmaxf(m1, __shfl_xor(m1, off, 64));
    }
    __shared__ float sred[2][4];
    if (lane == 0) { sred[0][wv] = m0; sred[1][wv] = m1; }
    __syncthreads();
    m0 = fmaxf(fmaxf(sred[0][0], sred[0][1]), fmaxf(sred[0][2], sred[0][3]));
    m1 = fmaxf(fmaxf(sred[1][0], sred[1][1]), fmaxf(sred[1][2], sred[1][3]));
    float p0[4], p1[4], s0 = 0.f, s1 = 0.f;
#pragma unroll
    for (int j = 0; j < 4; j++) {
        p0[j] = expf(v0[j] - m0); s0 += p0[j];
        p1[j] = expf(v1[j] - m1); s1 += p1[j];
    }
#pragma unroll
    for (int off = 32; off; off >>= 1) {
        s0 += __shfl_xor(s0, off, 64);
        s1 += __shfl_xor(s1, off, 64);
    }
    __shared__ float sred2[2][4];
    if (lane == 0) { sred2[0][wv] = s0; sred2[1][wv] = s1; }
    __syncthreads();
    s0 = sred2[0][0] + sred2[0][1] + sred2[0][2] + sred2[0][3];
    s1 = sred2[1][0] + sred2[1][1] + sred2[1][2] + sred2[1][3];
    const float c0 = gates[2 * b] / s0;
    const float c1 = gates[2 * b + 1] / s1;
#pragma unroll
    for (int j = 0; j < 4; j++) {
        float c = p0[j] * c0 + p1[j] * c1;
        if (c == 0.f) c = 2.2204460492503131e-16f;  // np.finfo(float64).eps
        y[(size_t)b * DD + tid + 256 * j] = logf(c);
    }
}

extern "C" void kernel_launch(void* const* d_in, const int* in_sizes, int n_in,
                              void* d_out, int out_size, void* d_ws, size_t ws_size,
                              hipStream_t stream) {
    const float* x     = (const float*)d_in[0];
    const float* wgate = (const float*)d_in[1];
    const float* fc1w  = (const float*)d_in[2];
    const float* fc1b  = (const float*)d_in[3];
    const float* fc2w  = (const float*)d_in[4];
    const float* fc2b  = (const float*)d_in[5];
    float* out = (float*)d_out;

    char* ws = (char*)d_ws;
    const size_t MB = 1024 * 1024;
    // big layout (289 MiB): [0,64) w1b (later o fp32, exactly 64 MiB)
    //                       [64,128) w2b; [128,256) h bf16 packed; [256,288) xg; meta@288
    // small layout (273 MiB): [0,64) w1b/o; [64,128) w2b; [128,144) xb; [144,272) h; meta@272
    const bool big = ws_size >= 289 * MB;
    u16* w1b = (u16*)(ws);
    float* o = (float*)(ws);
    u16* w2b = (u16*)(ws + 64 * MB);
    u16* xb  = (u16*)(ws + 128 * MB);              // small path only
    u16* h   = (u16*)(ws + (big ? 128 : 144) * MB);
    u16* xg  = (u16*)(ws + 256 * MB);              // big path only
    char* meta = ws + (big ? 288 : 272) * MB;
    int* counts       = (int*)meta;                 // 32 B
    int* offs         = (int*)(meta + 32);          // 32 B
    float* importance = (float*)(meta + 64);        // 32 B
    float* gate_arr   = (float*)(meta + 128);       // 64 KiB
    int* info         = (int*)(meta + 128 + 65536); // 64 KiB
    int* list         = (int*)(meta + 128 + 131072);// 256 KiB

    hipMemsetAsync(meta, 0, 96, stream);  // counts + offs + importance
    cvt_kernel<<<(EE * HH * DD / 8 + 255) / 256, 256, 0, stream>>>(fc1w, w1b, EE * HH * DD / 8);
    cvt_kernel<<<(EE * DD * HH / 8 + 255) / 256, 256, 0, stream>>>(fc2w, w2b, EE * DD * HH / 8);
    gating_kernel<<<BT / 4, 256, 0, stream>>>(x, wgate, gate_arr, list, info, counts, importance);
    loss_kernel<<<1, 64, 0, stream>>>(counts, importance, offs, out + (size_t)BT * DD);

    if (big) {
        gather_x_kernel<<<2 * BT, 256, 0, stream>>>(x, list, counts, offs, xg);
        moe_gemm<DD, HH, true, false><<<dim3(HH / 128, BT / 128, EE), 256, 0, stream>>>(
            xg, w1b, fc1b, nullptr, counts, offs, h, nullptr);
    } else {
        cvt_kernel<<<(BT * DD / 8 + 255) / 256, 256, 0, stream>>>(x, xb, BT * DD / 8);
        moe_gemm<DD, HH, true, true><<<dim3(HH / 128, BT / 128, EE), 256, 0, stream>>>(
            xb, w1b, fc1b, list, counts, offs, h, nullptr);
    }
    // pass B: o = h @ fc2_w^T + fc2_b ; A rows contiguous (packed), o packed.
    moe_gemm<HH, DD, false, false><<<dim3(DD / 128, BT / 128, EE), 256, 0, stream>>>(
        h, w2b, fc2b, nullptr, counts, offs, nullptr, o);
    combine_kernel<<<BT, 256, 0, stream>>>(o, gate_arr, info, offs, out);
}